// Round 7
// baseline (455738.965 us; speedup 1.0000x reference)
//
#include <hip/hip_runtime.h>
#include <cstdint>

// TinyVanillaRNN: T=16384 sequential steps h = tanh(U[:,x_t] + W h + bh);
// logits[t] = V h_t + by. out = [logits (T*O) | h_T (H)], fp32.
//
// R7: barrier-free, LDS-staging-free recurrence.
// 256 blocks launched; XCD election (R5/R6-proven) picks 32 co-XCD workers.
// Thread = 4 W-rows x 16 k's. Each thread polls its OWN 16 h values directly
// from the tagged global buffer (16 volatile u64 loads, local-L2 in fast
// mode) -> no ds_write/__syncthreads/ds_read per step (R6 proved the 2^26
// conflict counter came from the staged b128 reads, and R3's ~1100cy LDS
// term was staging+shuffles). Reduce = DPP quad_perm/ror ladder (R6-verified)
// + ds_swizzle xor16 + shfl_xor 32; full row sums land in ALL lanes, lanes
// 0..3 publish 4 coalesced tagged u64 (32B write-through, no amplification).
// Logits (V rows 2/wave) reuse the polled h regs in the post-publish shadow.
// Buffer safety without barriers: wave publishes t+2 only after seeing all
// tags t+1, which requires every wave (all blocks) to have published t+1,
// which requires them to have consumed all of parity-(t&1). Canary handshake
// falls back to agent-scope atomics if the fast channel is dead (hang-proof).

constexpr int T_STEPS = 16384;
constexpr int D_DIM   = 512;
constexpr int H_DIM   = 1024;
constexpr int O_DIM   = 512;
constexpr int NGRID   = 256;
constexpr int NWORK   = 32;
constexpr int NTHR    = 512;

typedef float v2f __attribute__((ext_vector_type(2)));

__device__ __forceinline__ float fast_tanh(float x) {
    float e = __expf(2.f * x);
    return 1.f - 2.f / (e + 1.f);
}

template<int CTRL>
__device__ __forceinline__ float dpp_mov(float x) {
    return __int_as_float(__builtin_amdgcn_update_dpp(
        0, __float_as_int(x), CTRL, 0xf, 0xf, true));
}
__device__ __forceinline__ float swz_xor16(float x) {
    return __int_as_float(__builtin_amdgcn_ds_swizzle(__float_as_int(x), 0x401F));
}

// Sum s[j] over all 64 lanes; returns full sum of row (l&3) in EVERY lane.
__device__ __forceinline__ float reduce4(float s0, float s1, float s2, float s3, int l) {
    const bool o1 = (l & 1) != 0, o2 = (l & 2) != 0;
    float A  = o1 ? s1 : s0, Ax = o1 ? s0 : s1;
    A += dpp_mov<0xB1>(Ax);            // quad_perm [1,0,3,2] = xor1
    float B  = o1 ? s3 : s2, Bx = o1 ? s2 : s3;
    B += dpp_mov<0xB1>(Bx);
    float C  = o2 ? B : A, Cx = o2 ? A : B;
    C += dpp_mov<0x4E>(Cx);            // quad_perm [2,3,0,1] = xor2
    C += dpp_mov<0x124>(C);            // row_ror:4
    C += dpp_mov<0x128>(C);            // row_ror:8 -> row16 sums, all lanes
    C += swz_xor16(C);                 // xor16 (within 32-lane half)
    C += __shfl_xor(C, 32);            // cross-half
    return C;
}
// Same for 2 rows; full sum of row (l&1) in every lane.
__device__ __forceinline__ float reduce2(float s0, float s1, int l) {
    const bool o1 = (l & 1) != 0;
    float A  = o1 ? s1 : s0, Ax = o1 ? s0 : s1;
    A += dpp_mov<0xB1>(Ax);
    A += dpp_mov<0x4E>(A);
    A += dpp_mov<0x124>(A);
    A += dpp_mov<0x128>(A);
    A += swz_xor16(A);
    A += __shfl_xor(A, 32);
    return A;
}

// Poll this thread's 16 tagged words until all carry `want`; unpack to v2f[8].
__device__ __forceinline__ void poll_h16(const unsigned long long* htag, size_t base,
                                         unsigned want, bool fast, v2f h2[8]) {
    unsigned long long r[16];
    bool ok;
    if (fast) {
        const volatile unsigned long long* fp = htag + base;
        do {
#pragma unroll
            for (int q = 0; q < 16; ++q) r[q] = fp[q];
            ok = true;
#pragma unroll
            for (int q = 0; q < 16; ++q) ok = ok && ((unsigned)(r[q] >> 32) == want);
        } while (!__all(ok));
    } else {
        const unsigned long long* sp = htag + base;
        do {
#pragma unroll
            for (int q = 0; q < 16; ++q)
                r[q] = __hip_atomic_load(sp + q, __ATOMIC_RELAXED, __HIP_MEMORY_SCOPE_AGENT);
            ok = true;
#pragma unroll
            for (int q = 0; q < 16; ++q) ok = ok && ((unsigned)(r[q] >> 32) == want);
        } while (!__all(ok));
    }
#pragma unroll
    for (int q = 0; q < 8; ++q)
        h2[q] = v2f{__uint_as_float((unsigned)r[2 * q]),
                    __uint_as_float((unsigned)r[2 * q + 1])};
}

__global__ __launch_bounds__(NTHR, 2)
void rnn_fused(const int* __restrict__ xs, const float* __restrict__ h0,
               const float* __restrict__ U, const float* __restrict__ W,
               const float* __restrict__ V, const float* __restrict__ bh,
               const float* __restrict__ by, float* __restrict__ out,
               int* __restrict__ ctrl, unsigned long long* __restrict__ htag)
{
    const int tid = threadIdx.x;

    // ---- election + canary (R5/R6-proven) ----
    __shared__ int s_slice, s_mode;
    if (tid == 0) {
        int xcd;
        asm volatile("s_getreg_b32 %0, hwreg(HW_REG_XCC_ID)" : "=s"(xcd));
        xcd &= 7;
        const int r = __hip_atomic_fetch_add(&ctrl[1 + xcd], 1,
                                             __ATOMIC_RELAXED, __HIP_MEMORY_SCOPE_AGENT);
        if (r == NWORK - 1) {
            int expected = 0;
            __hip_atomic_compare_exchange_strong(&ctrl[0], &expected, xcd + 1,
                __ATOMIC_RELAXED, __ATOMIC_RELAXED, __HIP_MEMORY_SCOPE_AGENT);
        }
        int ch;
        do {
            ch = __hip_atomic_load(&ctrl[0], __ATOMIC_RELAXED, __HIP_MEMORY_SCOPE_AGENT);
        } while (ch == 0);
        const int slice = (ch - 1 == xcd && r < NWORK) ? r : -1;
        s_slice = slice;

        int mode = 0;
        if (slice >= 0) {
            ((volatile int*)ctrl)[16 + slice] = 0x5EED0000 | slice;
            if (slice == 0) {
                mode = 1;
                for (int pass = 0; pass < (1 << 17); ++pass) {
                    bool all = true;
                    for (int rr = 0; rr < NWORK; ++rr)
                        if (((volatile int*)ctrl)[16 + rr] != (0x5EED0000 | rr)) { all = false; break; }
                    if (all) break;
                    if (pass == (1 << 17) - 1) mode = 2;
                }
                __hip_atomic_store(&ctrl[9], mode, __ATOMIC_RELAXED, __HIP_MEMORY_SCOPE_AGENT);
            } else {
                do {
                    mode = __hip_atomic_load(&ctrl[9], __ATOMIC_RELAXED, __HIP_MEMORY_SCOPE_AGENT);
                } while (mode == 0);
            }
        }
        s_mode = mode;
    }
    __syncthreads();
    const int b = s_slice;
    if (b < 0) return;
    const bool fast = (s_mode == 1);

    const int w = tid >> 6;             // wave 0..7
    const int l = tid & 63;             // lane

    // ---- W fragment: rows wr0..wr0+3, k in [16l, 16l+16) ----
    const int wr0 = b * 32 + w * 4;
    v2f wreg[4][8];
#pragma unroll
    for (int j = 0; j < 4; ++j)
#pragma unroll
        for (int q = 0; q < 8; ++q)
            wreg[j][q] = *(const v2f*)(W + (size_t)(wr0 + j) * H_DIM + 16 * l + 2 * q);
    const float bh_r = bh[wr0 + (l & 3)];

    // ---- V fragment: rows vr0, vr0+1, same k-chunk ----
    const int vr0 = b * 16 + w * 2;
    v2f vreg[2][8];
#pragma unroll
    for (int m = 0; m < 2; ++m)
#pragma unroll
        for (int q = 0; q < 8; ++q)
            vreg[m][q] = *(const v2f*)(V + (size_t)(vr0 + m) * H_DIM + 16 * l + 2 * q);
    const float by_r = by[vr0 + (l & 1)];

    for (int t = 0; t < T_STEPS; ++t) {
        // prefetch (independent of poll; completes under detection latency)
        const int xt = xs[t];
        float uv = 0.f;
        if (l < 4) uv = U[(size_t)(wr0 + l) * D_DIM + xt];

        // ---- acquire the 16 h floats this thread consumes ----
        v2f h2[8];
        if (t == 0) {
            const float* hp = h0 + 16 * l;
#pragma unroll
            for (int q = 0; q < 8; ++q) h2[q] = *(const v2f*)(hp + 2 * q);
        } else {
            poll_h16(htag, (size_t)((t - 1) & 1) * H_DIM + 16 * l,
                     (unsigned)(t - 1), fast, h2);
        }

        // ---- critical path: 32 pk-FMA, DPP reduce, tanh, publish ----
        v2f a0 = v2f{0.f, 0.f}, a1 = v2f{0.f, 0.f}, a2 = v2f{0.f, 0.f}, a3 = v2f{0.f, 0.f};
#pragma unroll
        for (int q = 0; q < 8; ++q) {
            a0 = __builtin_elementwise_fma(wreg[0][q], h2[q], a0);
            a1 = __builtin_elementwise_fma(wreg[1][q], h2[q], a1);
            a2 = __builtin_elementwise_fma(wreg[2][q], h2[q], a2);
            a3 = __builtin_elementwise_fma(wreg[3][q], h2[q], a3);
        }
        const float C = reduce4(a0.x + a0.y, a1.x + a1.y,
                                a2.x + a2.y, a3.x + a3.y, l);

        if (l < 4) {
            const float hv = fast_tanh(C + bh_r + uv);
            const unsigned long long pk =
                ((unsigned long long)(unsigned)t << 32) | (unsigned long long)__float_as_uint(hv);
            unsigned long long* dst = htag + (size_t)(t & 1) * H_DIM + wr0 + l;
            if (fast) *(volatile unsigned long long*)dst = pk;   // coalesced 32B/wave
            else __hip_atomic_store(dst, pk, __ATOMIC_RELAXED, __HIP_MEMORY_SCOPE_AGENT);
        }

        // ---- shadow: logits[t-1] from the same h2 registers ----
        if (t > 0) {
            v2f e0 = v2f{0.f, 0.f}, e1 = v2f{0.f, 0.f};
#pragma unroll
            for (int q = 0; q < 8; ++q) {
                e0 = __builtin_elementwise_fma(vreg[0][q], h2[q], e0);
                e1 = __builtin_elementwise_fma(vreg[1][q], h2[q], e1);
            }
            const float P = reduce2(e0.x + e0.y, e1.x + e1.y, l);
            if (l < 2) out[(size_t)(t - 1) * O_DIM + vr0 + l] = P + by_r;
        }
    }

    // ---- epilogue: h_T (tag T-1, parity 1) + logits[T-1] ----
    {
        v2f h2[8];
        poll_h16(htag, (size_t)((T_STEPS - 1) & 1) * H_DIM + 16 * l,
                 (unsigned)(T_STEPS - 1), fast, h2);

        if (b == 0 && w == 0) {
            float* op = out + (size_t)T_STEPS * O_DIM + 16 * l;
#pragma unroll
            for (int q = 0; q < 8; ++q)
                *(float2*)(op + 2 * q) = make_float2(h2[q].x, h2[q].y);
        }

        v2f e0 = v2f{0.f, 0.f}, e1 = v2f{0.f, 0.f};
#pragma unroll
        for (int q = 0; q < 8; ++q) {
            e0 = __builtin_elementwise_fma(vreg[0][q], h2[q], e0);
            e1 = __builtin_elementwise_fma(vreg[1][q], h2[q], e1);
        }
        const float P = reduce2(e0.x + e0.y, e1.x + e1.y, l);
        if (l < 2) out[(size_t)(T_STEPS - 1) * O_DIM + vr0 + l] = P + by_r;
    }
}

extern "C" void kernel_launch(void* const* d_in, const int* in_sizes, int n_in,
                              void* d_out, int out_size, void* d_ws, size_t ws_size,
                              hipStream_t stream) {
    const int*   xs = (const int*)d_in[0];
    const float* h0 = (const float*)d_in[1];
    const float* U  = (const float*)d_in[2];
    const float* W  = (const float*)d_in[3];
    const float* V  = (const float*)d_in[4];
    const float* bh = (const float*)d_in[5];
    const float* by = (const float*)d_in[6];
    float* out = (float*)d_out;

    // ws: [ctrl 256 B: chosen@0, cnt[8]@1..8, mode@9, canaries@16..47]
    //     [htag 2*1024 u64]
    int* ctrl = (int*)d_ws;
    unsigned long long* htag = (unsigned long long*)((char*)d_ws + 256);

    hipMemsetAsync(d_ws, 0, 256, stream);
    hipMemsetAsync((char*)d_ws + 256, 0xAA,
                   2 * H_DIM * sizeof(unsigned long long), stream);

    rnn_fused<<<NGRID, NTHR, 0, stream>>>(xs, h0, U, W, V, bh, by, out, ctrl, htag);
}